// Round 7
// baseline (179.155 us; speedup 1.0000x reference)
//
#include <hip/hip_runtime.h>
#include <hip/hip_bf16.h>

#define N_PTS 65536
#define LOG2E 1.4426950408889634f
#define INV2PI 0.15915494309189535f

typedef __attribute__((ext_vector_type(8))) short short8;
typedef __attribute__((ext_vector_type(4))) short short4v;
typedef __attribute__((ext_vector_type(4))) float float4v;
typedef __attribute__((ext_vector_type(4))) unsigned int uint4v;

#if __has_builtin(__builtin_amdgcn_exp2f)
#define EXP2F(x) __builtin_amdgcn_exp2f(x)
#else
#define EXP2F(x) exp2f(x)
#endif

// cos on REVOLUTIONS (inputs pre-scaled by 1/2pi in prep): v_fract + v_cos.
#if __has_builtin(__builtin_amdgcn_cosf) && __has_builtin(__builtin_amdgcn_fractf)
#define COSR(x) __builtin_amdgcn_cosf(__builtin_amdgcn_fractf(x))
#else
#define COSR(x) __cosf((x) * 6.283185307179586f)
#endif

__device__ __forceinline__ short f2b(float f) {
    __hip_bfloat16 h = __float2bfloat16(f);
    return *(short*)&h;
}
__device__ __forceinline__ float b2f(short s) {
    __hip_bfloat16 h = *(__hip_bfloat16*)&s;
    return __bfloat162float(h);
}

// Cheap packed f32x2 -> bf16x2: round-half-away (bits + 0x8000, truncate).
// Same 0.5-ulp bound as RNE (ties measure-zero); pure integer ops, no
// asm/union (R4/R5 failure modes avoided). low16 = a, high16 = b.
__device__ __forceinline__ unsigned int pkbf(float a, float b) {
    unsigned int ua = __builtin_bit_cast(unsigned int, a) + 0x8000u;
    unsigned int ub = __builtin_bit_cast(unsigned int, b) + 0x8000u;
    return (ua >> 16) | (ub & 0xFFFF0000u);
}

// ---- producer MFMA: K=16 native if available, else masked 16x16x32.
#if __has_builtin(__builtin_amdgcn_mfma_f32_16x16x16bf16_1k)
#define HAVE_MFMA16 1
typedef short4v pafrag;
__device__ __forceinline__ float4v pmfma(pafrag a, pafrag b, float4v c) {
    return __builtin_amdgcn_mfma_f32_16x16x16bf16_1k(a, b, c, 0, 0, 0);
}
#else
#define HAVE_MFMA16 0
typedef short8 pafrag;
__device__ __forceinline__ float4v pmfma(pafrag a, pafrag b, float4v c) {
    return __builtin_amdgcn_mfma_f32_16x16x32_bf16(a, b, c, 0, 0, 0);
}
#endif

// A-fragment from a [rows][16] bf16 table: lane (q,c) -> row base+c, k-dims.
__device__ __forceinline__ pafrag ldrow(const short* base, int row16, int q, int c) {
#if HAVE_MFMA16
    return *(const pafrag*)(base + (size_t)(row16 + c) * 16 + 4 * q);
#else
    pafrag v = (pafrag)0;
    if (q < 2) v = *(const pafrag*)(base + (size_t)(row16 + c) * 16 + 8 * q);
    return v;
#endif
}
// B-fragment from x (f32 [n][16]): lane (q,c) -> col row, k-dims.
__device__ __forceinline__ pafrag mkxfrag(const float* x, size_t row, int q) {
#if HAVE_MFMA16
    float4v v = *(const float4v*)(x + row * 16 + 4 * q);
    pafrag a;
    a[0] = f2b(v.x); a[1] = f2b(v.y); a[2] = f2b(v.z); a[3] = f2b(v.w);
    return a;
#else
    pafrag a = (pafrag)0;
    if (q < 2) {
        const float4v* xp = (const float4v*)(x + row * 16 + 8 * q);
        float4v v0 = xp[0], v1 = xp[1];
        a[0] = f2b(v0.x); a[1] = f2b(v0.y); a[2] = f2b(v0.z); a[3] = f2b(v0.w);
        a[4] = f2b(v1.x); a[5] = f2b(v1.y); a[6] = f2b(v1.z); a[7] = f2b(v1.w);
    }
    return a;
#endif
}

// K-permutation: within each 32-row group, storage row p holds source row
// perm(p). Chunk A (p<16) -> m {0-3,8-11,16-19,24-27}; chunk B -> +4.
// Producer D-reg r at lane q (chunk A row 4q+r) => m = 8q+r; chunk B => 8q+4+r.
// So [dA[0..3], dB[0..3]] at lane q == consumer B-fragment k = 8q..8q+7. No LDS.
__device__ __forceinline__ int permrow(int p) {
    return ((p & 12) << 1) + (p & 3) + ((p >> 4) << 2);
}

// ---------------- prep (unchanged from R6) ----------------
// ws layout (bytes):
//   zb   [1024][16] bf16  @ 0        row-PERMUTED bf16(log2e * z)
//   FbB  [512][16] bf16   @ 32768    row-PERMUTED bf16(F^T / 2pi)  (rows = o*64+l)
//   BWd  [64][512] bf16   @ 49152    block-diag sqrt(2/64)*pw (natural cols)
//   Wtb  [64][1024] bf16  @ 114688   bf16(W) (natural cols)
//   nz2P [1024] f32       @ 245760   PERMUTED  -0.5*log2e*||bf16(z_m)||^2
//   phP  [512] f32        @ 249856   PERMUTED  phases / 2pi
__global__ __launch_bounds__(256) void prep_kernel(
    const float* __restrict__ z, const float* __restrict__ W,
    const float* __restrict__ F, const float* __restrict__ pw,
    const float* __restrict__ ph,
    short* __restrict__ zb, short* __restrict__ FbB,
    short* __restrict__ BWd, short* __restrict__ Wtb,
    float* __restrict__ nz2P, float* __restrict__ phP)
{
    int t = blockIdx.x * 256 + threadIdx.x;
    if (t < 16384) {
        int row = t >> 4, i = t & 15;
        int src = (row & ~31) + permrow(row & 31);
        zb[t] = f2b(LOG2E * z[src * 16 + i]);
    } else if (t < 17408) {
        int m = t - 16384;
        int src = (m & ~31) + permrow(m & 31);
        const float4v* zp = (const float4v*)(z + (size_t)src * 16);
        float s = 0.f;
        #pragma unroll
        for (int k = 0; k < 4; k++) {
            float4v v = zp[k];
            float a0 = b2f(f2b(v.x)), a1 = b2f(f2b(v.y));
            float a2 = b2f(f2b(v.z)), a3 = b2f(f2b(v.w));
            s += a0 * a0 + a1 * a1 + a2 * a2 + a3 * a3;
        }
        nz2P[m] = -(0.5f * LOG2E * s);
    } else if (t < 25600) {
        int p = t - 17408;
        int row = p >> 4, i = p & 15;
        int srow = (row & ~31) + permrow(row & 31);
        int o = srow >> 6, l = srow & 63;
        FbB[p] = f2b(INV2PI * F[o * 1024 + i * 64 + l]);
    } else if (t < 58368) {
        int p = t - 25600;
        int so = p >> 9, ol = p & 511, o = ol >> 6;
        float v = ((so & 7) == o) ? 0.17677669529663687f * pw[so * 64 + (ol & 63)] : 0.f;
        BWd[p] = f2b(v);
    } else if (t < 123904) {
        int p = t - 58368;
        Wtb[p] = f2b(W[p]);
    } else {
        int j = t - 123904;                    // 512 phases
        int sj = (j & ~31) + permrow(j & 31);
        phP[j] = INV2PI * ph[sj];
    }
}

// ---------------- fused: n-split waves, tiny accumulator, zero epilogue ----
// Each wave owns 16 n-columns x all 64 so x FULL K (1024 m + 512 l).
// acc[4] = 16 AGPR (was 64) -> ~45 VGPRs freed for chunk-ahead pipelining;
// waves own disjoint output columns -> direct stores, no LDS reduction.
// 128-thread blocks (2 waves, 32 n), grid 2048, target ~20 waves/CU.
__global__ __launch_bounds__(128, 5) void fused_kernel(
    const float* __restrict__ x,
    const short* __restrict__ zb, const short* __restrict__ FbB,
    const short* __restrict__ BWd, const short* __restrict__ Wtb,
    const float* __restrict__ nz2P, const float* __restrict__ phP,
    float* __restrict__ out)
{
    __shared__ float x2c[32];

    const int tid = threadIdx.x;
    const int lane = tid & 63, w = tid >> 6;     // w in {0,1}
    const int q = lane >> 4, c = lane & 15;
    const int n0 = blockIdx.x * 32;              // block covers 32 n
    const int nw = n0 + w * 16;                  // wave's 16 columns

    if (tid < 32) {
        float s = 0.f;
        const float4v* xr = (const float4v*)(x + (size_t)(n0 + tid) * 16);
        #pragma unroll
        for (int k = 0; k < 4; k++) {
            float4v v = xr[k];
            float a0 = b2f(f2b(v.x)), a1 = b2f(f2b(v.y));
            float a2 = b2f(f2b(v.z)), a3 = b2f(f2b(v.w));
            s += a0 * a0 + a1 * a1 + a2 * a2 + a3 * a3;
        }
        x2c[tid] = 0.5f * LOG2E * s;
    }

    // wave's x B-fragment (16 cols)
    pafrag ax = mkxfrag(x, (size_t)(nw + c), q);

    float4v acc[4];
    #pragma unroll
    for (int a = 0; a < 4; a++) acc[a] = (float4v)(0.f);

    __syncthreads();   // x2c ready

    // ============ data: exp2(x.z*log2e - z2) @ W^T, full 1024 m ============
    #pragma unroll 2
    for (int mb = 0; mb < 32; mb++) {
        const int m0 = mb * 32;
        pafrag bzA = ldrow(zb, m0, q, c);
        pafrag bzB = ldrow(zb, m0 + 16, q, c);
        float4v c0A = *(const float4v*)(nz2P + m0 + 4 * q);
        float4v c0B = *(const float4v*)(nz2P + m0 + 16 + 4 * q);
        short8 aw0 = *(const short8*)(Wtb + (size_t)(0 * 16 + c) * 1024 + m0 + q * 8);
        short8 aw1 = *(const short8*)(Wtb + (size_t)(1 * 16 + c) * 1024 + m0 + q * 8);
        short8 aw2 = *(const short8*)(Wtb + (size_t)(2 * 16 + c) * 1024 + m0 + q * 8);
        short8 aw3 = *(const short8*)(Wtb + (size_t)(3 * 16 + c) * 1024 + m0 + q * 8);
        float4v dA = pmfma(bzA, ax, c0A);
        float4v dB = pmfma(bzB, ax, c0B);
        uint4v u;
        u[0] = pkbf(EXP2F(dA[0]), EXP2F(dA[1]));
        u[1] = pkbf(EXP2F(dA[2]), EXP2F(dA[3]));
        u[2] = pkbf(EXP2F(dB[0]), EXP2F(dB[1]));
        u[3] = pkbf(EXP2F(dB[2]), EXP2F(dB[3]));
        short8 pb = __builtin_bit_cast(short8, u);
        acc[0] = __builtin_amdgcn_mfma_f32_16x16x32_bf16(aw0, pb, acc[0], 0, 0, 0);
        acc[1] = __builtin_amdgcn_mfma_f32_16x16x32_bf16(aw1, pb, acc[1], 0, 0, 0);
        acc[2] = __builtin_amdgcn_mfma_f32_16x16x32_bf16(aw2, pb, acc[2], 0, 0, 0);
        acc[3] = __builtin_amdgcn_mfma_f32_16x16x32_bf16(aw3, pb, acc[3], 0, 0, 0);
    }

    // scale data part by exp2(-x2[n])
    {
        float sxv = EXP2F(-x2c[w * 16 + c]);
        #pragma unroll
        for (int a = 0; a < 4; a++) acc[a] *= sxv;
    }

    // ============ prior: cos(2pi*(x.F/2pi + ph/2pi)) @ blockdiag(pws) ============
    #pragma unroll 2
    for (int lb = 0; lb < 16; lb++) {
        const int l0 = lb * 32;
        pafrag bfA = ldrow(FbB, l0, q, c);
        pafrag bfB = ldrow(FbB, l0 + 16, q, c);
        float4v c0A = *(const float4v*)(phP + l0 + 4 * q);
        float4v c0B = *(const float4v*)(phP + l0 + 16 + 4 * q);
        short8 aw0 = *(const short8*)(BWd + (size_t)(0 * 16 + c) * 512 + l0 + q * 8);
        short8 aw1 = *(const short8*)(BWd + (size_t)(1 * 16 + c) * 512 + l0 + q * 8);
        short8 aw2 = *(const short8*)(BWd + (size_t)(2 * 16 + c) * 512 + l0 + q * 8);
        short8 aw3 = *(const short8*)(BWd + (size_t)(3 * 16 + c) * 512 + l0 + q * 8);
        float4v dA = pmfma(bfA, ax, c0A);
        float4v dB = pmfma(bfB, ax, c0B);
        uint4v u;
        u[0] = pkbf(COSR(dA[0]), COSR(dA[1]));
        u[1] = pkbf(COSR(dA[2]), COSR(dA[3]));
        u[2] = pkbf(COSR(dB[0]), COSR(dB[1]));
        u[3] = pkbf(COSR(dB[2]), COSR(dB[3]));
        short8 pb = __builtin_bit_cast(short8, u);
        acc[0] = __builtin_amdgcn_mfma_f32_16x16x32_bf16(aw0, pb, acc[0], 0, 0, 0);
        acc[1] = __builtin_amdgcn_mfma_f32_16x16x32_bf16(aw1, pb, acc[1], 0, 0, 0);
        acc[2] = __builtin_amdgcn_mfma_f32_16x16x32_bf16(aw2, pb, acc[2], 0, 0, 0);
        acc[3] = __builtin_amdgcn_mfma_f32_16x16x32_bf16(aw3, pb, acc[3], 0, 0, 0);
    }

    // ============ direct store (wave owns disjoint columns) ============
    #pragma unroll
    for (int a = 0; a < 4; a++) {
        #pragma unroll
        for (int r = 0; r < 4; r++) {
            out[(size_t)(a * 16 + 4 * q + r) * N_PTS + nw + c] = acc[a][r];
        }
    }
}

extern "C" void kernel_launch(void* const* d_in, const int* in_sizes, int n_in,
                              void* d_out, int out_size, void* d_ws, size_t ws_size,
                              hipStream_t stream) {
    const float* x  = (const float*)d_in[0];   // [65536][16]
    const float* z  = (const float*)d_in[1];   // [1024][16]
    const float* W  = (const float*)d_in[2];   // [8][8][1024] = [64][1024]
    const float* F  = (const float*)d_in[3];   // [8][16][64]
    const float* ph = (const float*)d_in[4];   // [8][64]
    const float* pw = (const float*)d_in[5];   // [8][8][64] = [64][64]
    float* out = (float*)d_out;                // [64][65536]

    char* ws = (char*)d_ws;
    short* zb   = (short*)(ws);            // 32768 B
    short* FbB  = (short*)(ws + 32768);    // 16384 B
    short* BWd  = (short*)(ws + 49152);    // 65536 B
    short* Wtb  = (short*)(ws + 114688);   // 131072 B
    float* nz2P = (float*)(ws + 245760);   // 4096 B
    float* phP  = (float*)(ws + 249856);   // 2048 B

    prep_kernel<<<486, 256, 0, stream>>>(z, W, F, pw, ph, zb, FbB, BWd, Wtb, nz2P, phP);
    fused_kernel<<<2048, 128, 0, stream>>>(x, zb, FbB, BWd, Wtb, nz2P, phP, out);
}

// Round 8
// 116.164 us; speedup vs baseline: 1.5423x; 1.5423x over previous
//
#include <hip/hip_runtime.h>
#include <hip/hip_bf16.h>

#define N_PTS 65536
#define LOG2E 1.4426950408889634f
#define INV2PI 0.15915494309189535f

typedef __attribute__((ext_vector_type(8))) short short8;
typedef __attribute__((ext_vector_type(4))) short short4v;
typedef __attribute__((ext_vector_type(4))) float float4v;
typedef __attribute__((ext_vector_type(4))) unsigned int uint4v;

#if __has_builtin(__builtin_amdgcn_exp2f)
#define EXP2F(x) __builtin_amdgcn_exp2f(x)
#else
#define EXP2F(x) exp2f(x)
#endif

// cos on REVOLUTIONS (inputs pre-scaled by 1/2pi in prep): v_fract + v_cos.
#if __has_builtin(__builtin_amdgcn_cosf) && __has_builtin(__builtin_amdgcn_fractf)
#define COSR(x) __builtin_amdgcn_cosf(__builtin_amdgcn_fractf(x))
#else
#define COSR(x) __cosf((x) * 6.283185307179586f)
#endif

__device__ __forceinline__ short f2b(float f) {
    __hip_bfloat16 h = __float2bfloat16(f);
    return *(short*)&h;
}
__device__ __forceinline__ float b2f(short s) {
    __hip_bfloat16 h = *(__hip_bfloat16*)&s;
    return __bfloat162float(h);
}

// Cheap packed f32x2 -> bf16x2: round-half-away (bits + 0x8000, truncate).
// Same 0.5-ulp bound as RNE; pure integer ops (no asm/union — R4/R5 failure
// modes avoided). Verified in R7: identical absmax to the f2b chain.
// low16 = a, high16 = b.
__device__ __forceinline__ unsigned int pkbf(float a, float b) {
    unsigned int ua = __builtin_bit_cast(unsigned int, a) + 0x8000u;
    unsigned int ub = __builtin_bit_cast(unsigned int, b) + 0x8000u;
    return (ua >> 16) | (ub & 0xFFFF0000u);
}

// ---- producer MFMA: K=16 native if available, else masked 16x16x32.
#if __has_builtin(__builtin_amdgcn_mfma_f32_16x16x16bf16_1k)
#define HAVE_MFMA16 1
typedef short4v pafrag;
__device__ __forceinline__ float4v pmfma(pafrag a, pafrag b, float4v c) {
    return __builtin_amdgcn_mfma_f32_16x16x16bf16_1k(a, b, c, 0, 0, 0);
}
#else
#define HAVE_MFMA16 0
typedef short8 pafrag;
__device__ __forceinline__ float4v pmfma(pafrag a, pafrag b, float4v c) {
    return __builtin_amdgcn_mfma_f32_16x16x32_bf16(a, b, c, 0, 0, 0);
}
#endif

// A-fragment from a [rows][16] bf16 table: lane (q,c) -> row base+c, k-dims.
__device__ __forceinline__ pafrag ldrow(const short* base, int row16, int q, int c) {
#if HAVE_MFMA16
    return *(const pafrag*)(base + (size_t)(row16 + c) * 16 + 4 * q);
#else
    pafrag v = (pafrag)0;
    if (q < 2) v = *(const pafrag*)(base + (size_t)(row16 + c) * 16 + 8 * q);
    return v;
#endif
}
// B-fragment from x (f32 [n][16]): lane (q,c) -> col row, k-dims.
__device__ __forceinline__ pafrag mkxfrag(const float* x, size_t row, int q) {
#if HAVE_MFMA16
    float4v v = *(const float4v*)(x + row * 16 + 4 * q);
    pafrag a;
    a[0] = f2b(v.x); a[1] = f2b(v.y); a[2] = f2b(v.z); a[3] = f2b(v.w);
    return a;
#else
    pafrag a = (pafrag)0;
    if (q < 2) {
        const float4v* xp = (const float4v*)(x + row * 16 + 8 * q);
        float4v v0 = xp[0], v1 = xp[1];
        a[0] = f2b(v0.x); a[1] = f2b(v0.y); a[2] = f2b(v0.z); a[3] = f2b(v0.w);
        a[4] = f2b(v1.x); a[5] = f2b(v1.y); a[6] = f2b(v1.z); a[7] = f2b(v1.w);
    }
    return a;
#endif
}

// K-permutation: within each 32-row group, storage row p holds source row
// perm(p). Chunk A (p<16) -> m {0-3,8-11,16-19,24-27}; chunk B -> +4.
// Producer D-reg r at lane q (chunk A row 4q+r) => m = 8q+r; chunk B => 8q+4+r.
// So [dA[0..3], dB[0..3]] at lane q == consumer B-fragment k = 8q..8q+7. No LDS.
__device__ __forceinline__ int permrow(int p) {
    return ((p & 12) << 1) + (p & 3) + ((p >> 4) << 2);
}

// ---------------- prep (unchanged) ----------------
// ws layout (bytes):
//   zb   [1024][16] bf16  @ 0        row-PERMUTED bf16(log2e * z)
//   FbB  [512][16] bf16   @ 32768    row-PERMUTED bf16(F^T / 2pi)  (rows = o*64+l)
//   BWd  [64][512] bf16   @ 49152    block-diag sqrt(2/64)*pw (natural cols)
//   Wtb  [64][1024] bf16  @ 114688   bf16(W) (natural cols)
//   nz2P [1024] f32       @ 245760   PERMUTED  -0.5*log2e*||bf16(z_m)||^2
//   phP  [512] f32        @ 249856   PERMUTED  phases / 2pi
__global__ __launch_bounds__(256) void prep_kernel(
    const float* __restrict__ z, const float* __restrict__ W,
    const float* __restrict__ F, const float* __restrict__ pw,
    const float* __restrict__ ph,
    short* __restrict__ zb, short* __restrict__ FbB,
    short* __restrict__ BWd, short* __restrict__ Wtb,
    float* __restrict__ nz2P, float* __restrict__ phP)
{
    int t = blockIdx.x * 256 + threadIdx.x;
    if (t < 16384) {
        int row = t >> 4, i = t & 15;
        int src = (row & ~31) + permrow(row & 31);
        zb[t] = f2b(LOG2E * z[src * 16 + i]);
    } else if (t < 17408) {
        int m = t - 16384;
        int src = (m & ~31) + permrow(m & 31);
        const float4v* zp = (const float4v*)(z + (size_t)src * 16);
        float s = 0.f;
        #pragma unroll
        for (int k = 0; k < 4; k++) {
            float4v v = zp[k];
            float a0 = b2f(f2b(v.x)), a1 = b2f(f2b(v.y));
            float a2 = b2f(f2b(v.z)), a3 = b2f(f2b(v.w));
            s += a0 * a0 + a1 * a1 + a2 * a2 + a3 * a3;
        }
        nz2P[m] = -(0.5f * LOG2E * s);
    } else if (t < 25600) {
        int p = t - 17408;
        int row = p >> 4, i = p & 15;
        int srow = (row & ~31) + permrow(row & 31);
        int o = srow >> 6, l = srow & 63;
        FbB[p] = f2b(INV2PI * F[o * 1024 + i * 64 + l]);
    } else if (t < 58368) {
        int p = t - 25600;
        int so = p >> 9, ol = p & 511, o = ol >> 6;
        float v = ((so & 7) == o) ? 0.17677669529663687f * pw[so * 64 + (ol & 63)] : 0.f;
        BWd[p] = f2b(v);
    } else if (t < 123904) {
        int p = t - 58368;
        Wtb[p] = f2b(W[p]);
    } else {
        int j = t - 123904;                    // 512 phases
        int sj = (j & ~31) + permrow(j & 31);
        phP[j] = INV2PI * ph[sj];
    }
}

// ---------------- fused prior + data: register-direct, zero main-loop LDS ----
// R6 structure (4 waves, K-quarter each, 64 so x 64 n) +
//  (1) pkbf integer pack (validated R7) instead of the f2b chain,
//  (2) FULL unroll of both chunk loops (deeper load hoisting),
//  (3) s_setprio(1) around consumer MFMA cluster (independent-wave regime).
__global__ __launch_bounds__(256, 4) void fused_kernel(
    const float* __restrict__ x,
    const short* __restrict__ zb, const short* __restrict__ FbB,
    const short* __restrict__ BWd, const short* __restrict__ Wtb,
    const float* __restrict__ nz2P, const float* __restrict__ phP,
    float* __restrict__ out)
{
    __shared__ float x2c[64];
    __shared__ __align__(16) float rbufA[64 * 68];
    __shared__ __align__(16) float rbufB[64 * 68];

    const int tid = threadIdx.x;
    const int lane = tid & 63, w = tid >> 6;
    const int q = lane >> 4, c = lane & 15;
    const int n0 = blockIdx.x * 64;

    if (tid < 64) {
        float s = 0.f;
        const float4v* xr = (const float4v*)(x + (size_t)(n0 + tid) * 16);
        #pragma unroll
        for (int k = 0; k < 4; k++) {
            float4v v = xr[k];
            float a0 = b2f(f2b(v.x)), a1 = b2f(f2b(v.y));
            float a2 = b2f(f2b(v.z)), a3 = b2f(f2b(v.w));
            s += a0 * a0 + a1 * a1 + a2 * a2 + a3 * a3;
        }
        x2c[tid] = 0.5f * LOG2E * s;
    }

    // x B-fragments for the 4 n-groups
    pafrag ax[4];
    #pragma unroll
    for (int nt = 0; nt < 4; nt++)
        ax[nt] = mkxfrag(x, (size_t)(n0 + nt * 16 + c), q);

    float4v acc[4][4];
    #pragma unroll
    for (int a = 0; a < 4; a++)
        #pragma unroll
        for (int nt = 0; nt < 4; nt++) acc[a][nt] = (float4v)(0.f);

    __syncthreads();   // x2c ready

    // ============ data: exp2(x.z*log2e - z2) @ W^T, wave-private 256 m ============
    const int mbase = w * 256;
    #pragma unroll
    for (int mb = 0; mb < 8; mb++) {
        const int m0 = mbase + mb * 32;
        pafrag bzA = ldrow(zb, m0, q, c);
        pafrag bzB = ldrow(zb, m0 + 16, q, c);
        float4v c0A = *(const float4v*)(nz2P + m0 + 4 * q);
        float4v c0B = *(const float4v*)(nz2P + m0 + 16 + 4 * q);
        short8 aw0 = *(const short8*)(Wtb + (size_t)(0 * 16 + c) * 1024 + m0 + q * 8);
        short8 aw1 = *(const short8*)(Wtb + (size_t)(1 * 16 + c) * 1024 + m0 + q * 8);
        short8 aw2 = *(const short8*)(Wtb + (size_t)(2 * 16 + c) * 1024 + m0 + q * 8);
        short8 aw3 = *(const short8*)(Wtb + (size_t)(3 * 16 + c) * 1024 + m0 + q * 8);
        #pragma unroll
        for (int nt = 0; nt < 4; nt++) {
            float4v dA = pmfma(bzA, ax[nt], c0A);
            float4v dB = pmfma(bzB, ax[nt], c0B);
            uint4v u;
            u[0] = pkbf(EXP2F(dA[0]), EXP2F(dA[1]));
            u[1] = pkbf(EXP2F(dA[2]), EXP2F(dA[3]));
            u[2] = pkbf(EXP2F(dB[0]), EXP2F(dB[1]));
            u[3] = pkbf(EXP2F(dB[2]), EXP2F(dB[3]));
            short8 pb = __builtin_bit_cast(short8, u);
            __builtin_amdgcn_s_setprio(1);
            acc[0][nt] = __builtin_amdgcn_mfma_f32_16x16x32_bf16(aw0, pb, acc[0][nt], 0, 0, 0);
            acc[1][nt] = __builtin_amdgcn_mfma_f32_16x16x32_bf16(aw1, pb, acc[1][nt], 0, 0, 0);
            acc[2][nt] = __builtin_amdgcn_mfma_f32_16x16x32_bf16(aw2, pb, acc[2][nt], 0, 0, 0);
            acc[3][nt] = __builtin_amdgcn_mfma_f32_16x16x32_bf16(aw3, pb, acc[3][nt], 0, 0, 0);
            __builtin_amdgcn_s_setprio(0);
        }
    }

    // scale data part by exp2(-x2[n])
    #pragma unroll
    for (int nt = 0; nt < 4; nt++) {
        float sxv = EXP2F(-x2c[nt * 16 + c]);
        #pragma unroll
        for (int a = 0; a < 4; a++) acc[a][nt] *= sxv;
    }

    // ============ prior: cos(2pi*(x.F/2pi + ph/2pi)) @ blockdiag(pws) ============
    const int lbase = w * 128;
    #pragma unroll
    for (int lb = 0; lb < 4; lb++) {
        const int l0 = lbase + lb * 32;
        pafrag bfA = ldrow(FbB, l0, q, c);
        pafrag bfB = ldrow(FbB, l0 + 16, q, c);
        float4v c0A = *(const float4v*)(phP + l0 + 4 * q);
        float4v c0B = *(const float4v*)(phP + l0 + 16 + 4 * q);
        short8 aw0 = *(const short8*)(BWd + (size_t)(0 * 16 + c) * 512 + l0 + q * 8);
        short8 aw1 = *(const short8*)(BWd + (size_t)(1 * 16 + c) * 512 + l0 + q * 8);
        short8 aw2 = *(const short8*)(BWd + (size_t)(2 * 16 + c) * 512 + l0 + q * 8);
        short8 aw3 = *(const short8*)(BWd + (size_t)(3 * 16 + c) * 512 + l0 + q * 8);
        #pragma unroll
        for (int nt = 0; nt < 4; nt++) {
            float4v dA = pmfma(bfA, ax[nt], c0A);
            float4v dB = pmfma(bfB, ax[nt], c0B);
            uint4v u;
            u[0] = pkbf(COSR(dA[0]), COSR(dA[1]));
            u[1] = pkbf(COSR(dA[2]), COSR(dA[3]));
            u[2] = pkbf(COSR(dB[0]), COSR(dB[1]));
            u[3] = pkbf(COSR(dB[2]), COSR(dB[3]));
            short8 pb = __builtin_bit_cast(short8, u);
            __builtin_amdgcn_s_setprio(1);
            acc[0][nt] = __builtin_amdgcn_mfma_f32_16x16x32_bf16(aw0, pb, acc[0][nt], 0, 0, 0);
            acc[1][nt] = __builtin_amdgcn_mfma_f32_16x16x32_bf16(aw1, pb, acc[1][nt], 0, 0, 0);
            acc[2][nt] = __builtin_amdgcn_mfma_f32_16x16x32_bf16(aw2, pb, acc[2][nt], 0, 0, 0);
            acc[3][nt] = __builtin_amdgcn_mfma_f32_16x16x32_bf16(aw3, pb, acc[3][nt], 0, 0, 0);
            __builtin_amdgcn_s_setprio(0);
        }
    }

    // ============ epilogue: reduce 4 wave-partials, store ============
    __syncthreads();
    if (w & 1) {                       // w1 -> A, w3 -> B
        float* rb = (w == 1) ? rbufA : rbufB;
        #pragma unroll
        for (int a = 0; a < 4; a++)
            #pragma unroll
            for (int nt = 0; nt < 4; nt++)
                #pragma unroll
                for (int r = 0; r < 4; r++)
                    rb[(a * 16 + 4 * q + r) * 68 + nt * 16 + c] = acc[a][nt][r];
    }
    __syncthreads();
    if (!(w & 1)) {                    // w0 += into A, w2 += into B
        float* rb = (w == 0) ? rbufA : rbufB;
        #pragma unroll
        for (int a = 0; a < 4; a++)
            #pragma unroll
            for (int nt = 0; nt < 4; nt++)
                #pragma unroll
                for (int r = 0; r < 4; r++) {
                    int idx = (a * 16 + 4 * q + r) * 68 + nt * 16 + c;
                    rb[idx] += acc[a][nt][r];
                }
    }
    __syncthreads();
    #pragma unroll
    for (int k = 0; k < 16; k++) {     // out = A + B, row-coalesced
        int idx = k * 256 + tid;
        int row = idx >> 6, nn = idx & 63;
        out[(size_t)row * N_PTS + n0 + nn] = rbufA[row * 68 + nn] + rbufB[row * 68 + nn];
    }
}

extern "C" void kernel_launch(void* const* d_in, const int* in_sizes, int n_in,
                              void* d_out, int out_size, void* d_ws, size_t ws_size,
                              hipStream_t stream) {
    const float* x  = (const float*)d_in[0];   // [65536][16]
    const float* z  = (const float*)d_in[1];   // [1024][16]
    const float* W  = (const float*)d_in[2];   // [8][8][1024] = [64][1024]
    const float* F  = (const float*)d_in[3];   // [8][16][64]
    const float* ph = (const float*)d_in[4];   // [8][64]
    const float* pw = (const float*)d_in[5];   // [8][8][64] = [64][64]
    float* out = (float*)d_out;                // [64][65536]

    char* ws = (char*)d_ws;
    short* zb   = (short*)(ws);            // 32768 B
    short* FbB  = (short*)(ws + 32768);    // 16384 B
    short* BWd  = (short*)(ws + 49152);    // 65536 B
    short* Wtb  = (short*)(ws + 114688);   // 131072 B
    float* nz2P = (float*)(ws + 245760);   // 4096 B
    float* phP  = (float*)(ws + 249856);   // 2048 B

    prep_kernel<<<486, 256, 0, stream>>>(z, W, F, pw, ph, zb, FbB, BWd, Wtb, nz2P, phP);
    fused_kernel<<<1024, 256, 0, stream>>>(x, zb, FbB, BWd, Wtb, nz2P, phP, out);
}

// Round 9
// 108.730 us; speedup vs baseline: 1.6477x; 1.0684x over previous
//
#include <hip/hip_runtime.h>
#include <hip/hip_bf16.h>

#define N_PTS 65536
#define LOG2E 1.4426950408889634f
#define INV2PI 0.15915494309189535f

typedef __attribute__((ext_vector_type(8))) short short8;
typedef __attribute__((ext_vector_type(4))) short short4v;
typedef __attribute__((ext_vector_type(4))) float float4v;
typedef __attribute__((ext_vector_type(4))) unsigned int uint4v;

#if __has_builtin(__builtin_amdgcn_exp2f)
#define EXP2F(x) __builtin_amdgcn_exp2f(x)
#else
#define EXP2F(x) exp2f(x)
#endif

// cos on REVOLUTIONS (inputs pre-scaled by 1/2pi in prep): v_fract + v_cos.
#if __has_builtin(__builtin_amdgcn_cosf) && __has_builtin(__builtin_amdgcn_fractf)
#define COSR(x) __builtin_amdgcn_cosf(__builtin_amdgcn_fractf(x))
#else
#define COSR(x) __cosf((x) * 6.283185307179586f)
#endif

__device__ __forceinline__ short f2b(float f) {
    __hip_bfloat16 h = __float2bfloat16(f);
    return *(short*)&h;
}
__device__ __forceinline__ float b2f(short s) {
    __hip_bfloat16 h = *(__hip_bfloat16*)&s;
    return __bfloat162float(h);
}

// Cheap packed f32x2 -> bf16x2: round-half-away (bits + 0x8000, truncate).
// Same 0.5-ulp bound as RNE; pure integer ops (no asm/union — R4/R5 failure
// modes avoided). Numerically validated in R7 (identical absmax).
// low16 = a, high16 = b.
__device__ __forceinline__ unsigned int pkbf(float a, float b) {
    unsigned int ua = __builtin_bit_cast(unsigned int, a) + 0x8000u;
    unsigned int ub = __builtin_bit_cast(unsigned int, b) + 0x8000u;
    return (ua >> 16) | (ub & 0xFFFF0000u);
}

// ---- producer MFMA: K=16 native if available, else masked 16x16x32.
#if __has_builtin(__builtin_amdgcn_mfma_f32_16x16x16bf16_1k)
#define HAVE_MFMA16 1
typedef short4v pafrag;
__device__ __forceinline__ float4v pmfma(pafrag a, pafrag b, float4v c) {
    return __builtin_amdgcn_mfma_f32_16x16x16bf16_1k(a, b, c, 0, 0, 0);
}
#else
#define HAVE_MFMA16 0
typedef short8 pafrag;
__device__ __forceinline__ float4v pmfma(pafrag a, pafrag b, float4v c) {
    return __builtin_amdgcn_mfma_f32_16x16x32_bf16(a, b, c, 0, 0, 0);
}
#endif

// A-fragment from a [rows][16] bf16 table: lane (q,c) -> row base+c, k-dims.
__device__ __forceinline__ pafrag ldrow(const short* base, int row16, int q, int c) {
#if HAVE_MFMA16
    return *(const pafrag*)(base + (size_t)(row16 + c) * 16 + 4 * q);
#else
    pafrag v = (pafrag)0;
    if (q < 2) v = *(const pafrag*)(base + (size_t)(row16 + c) * 16 + 8 * q);
    return v;
#endif
}
// B-fragment from x (f32 [n][16]): lane (q,c) -> col row, k-dims.
__device__ __forceinline__ pafrag mkxfrag(const float* x, size_t row, int q) {
#if HAVE_MFMA16
    float4v v = *(const float4v*)(x + row * 16 + 4 * q);
    pafrag a;
    a[0] = f2b(v.x); a[1] = f2b(v.y); a[2] = f2b(v.z); a[3] = f2b(v.w);
    return a;
#else
    pafrag a = (pafrag)0;
    if (q < 2) {
        const float4v* xp = (const float4v*)(x + row * 16 + 8 * q);
        float4v v0 = xp[0], v1 = xp[1];
        a[0] = f2b(v0.x); a[1] = f2b(v0.y); a[2] = f2b(v0.z); a[3] = f2b(v0.w);
        a[4] = f2b(v1.x); a[5] = f2b(v1.y); a[6] = f2b(v1.z); a[7] = f2b(v1.w);
    }
    return a;
#endif
}

// K-permutation: within each 32-row group, storage row p holds source row
// perm(p). Chunk A (p<16) -> m {0-3,8-11,16-19,24-27}; chunk B -> +4.
// Producer D-reg r at lane q (chunk A row 4q+r) => m = 8q+r; chunk B => 8q+4+r.
// So [dA[0..3], dB[0..3]] at lane q == consumer B-fragment k = 8q..8q+7. No LDS.
__device__ __forceinline__ int permrow(int p) {
    return ((p & 12) << 1) + (p & 3) + ((p >> 4) << 2);
}

// ---------------- prep (unchanged) ----------------
// ws layout (bytes):
//   zb   [1024][16] bf16  @ 0        row-PERMUTED bf16(log2e * z)
//   FbB  [512][16] bf16   @ 32768    row-PERMUTED bf16(F^T / 2pi)  (rows = o*64+l)
//   BWd  [64][512] bf16   @ 49152    block-diag sqrt(2/64)*pw (natural cols)
//   Wtb  [64][1024] bf16  @ 114688   bf16(W) (natural cols)
//   nz2P [1024] f32       @ 245760   PERMUTED  -0.5*log2e*||bf16(z_m)||^2
//   phP  [512] f32        @ 249856   PERMUTED  phases / 2pi
__global__ __launch_bounds__(256) void prep_kernel(
    const float* __restrict__ z, const float* __restrict__ W,
    const float* __restrict__ F, const float* __restrict__ pw,
    const float* __restrict__ ph,
    short* __restrict__ zb, short* __restrict__ FbB,
    short* __restrict__ BWd, short* __restrict__ Wtb,
    float* __restrict__ nz2P, float* __restrict__ phP)
{
    int t = blockIdx.x * 256 + threadIdx.x;
    if (t < 16384) {
        int row = t >> 4, i = t & 15;
        int src = (row & ~31) + permrow(row & 31);
        zb[t] = f2b(LOG2E * z[src * 16 + i]);
    } else if (t < 17408) {
        int m = t - 16384;
        int src = (m & ~31) + permrow(m & 31);
        const float4v* zp = (const float4v*)(z + (size_t)src * 16);
        float s = 0.f;
        #pragma unroll
        for (int k = 0; k < 4; k++) {
            float4v v = zp[k];
            float a0 = b2f(f2b(v.x)), a1 = b2f(f2b(v.y));
            float a2 = b2f(f2b(v.z)), a3 = b2f(f2b(v.w));
            s += a0 * a0 + a1 * a1 + a2 * a2 + a3 * a3;
        }
        nz2P[m] = -(0.5f * LOG2E * s);
    } else if (t < 25600) {
        int p = t - 17408;
        int row = p >> 4, i = p & 15;
        int srow = (row & ~31) + permrow(row & 31);
        int o = srow >> 6, l = srow & 63;
        FbB[p] = f2b(INV2PI * F[o * 1024 + i * 64 + l]);
    } else if (t < 58368) {
        int p = t - 25600;
        int so = p >> 9, ol = p & 511, o = ol >> 6;
        float v = ((so & 7) == o) ? 0.17677669529663687f * pw[so * 64 + (ol & 63)] : 0.f;
        BWd[p] = f2b(v);
    } else if (t < 123904) {
        int p = t - 58368;
        Wtb[p] = f2b(W[p]);
    } else {
        int j = t - 123904;                    // 512 phases
        int sj = (j & ~31) + permrow(j & 31);
        phP[j] = INV2PI * ph[sj];
    }
}

// ---------------- fused prior + data: register-direct, zero main-loop LDS ----
// R6 structure (4 waves, K-quarter each, 64 so x 64 n) with:
//  (1) __launch_bounds__(256,3): ~170 combined regs (64 AGPR + ~106 VGPR)
//      -> no scratch spills (R2-R8 all spilled under the 128-reg cap);
//  (2) pkbf integer pack (R7-validated) instead of the f2b chain;
//  (3) s_setprio(1) around consumer MFMA cluster (independent-wave regime);
//  (4) unroll 2 (full unroll spilled catastrophically in R8).
__global__ __launch_bounds__(256, 3) void fused_kernel(
    const float* __restrict__ x,
    const short* __restrict__ zb, const short* __restrict__ FbB,
    const short* __restrict__ BWd, const short* __restrict__ Wtb,
    const float* __restrict__ nz2P, const float* __restrict__ phP,
    float* __restrict__ out)
{
    __shared__ float x2c[64];
    __shared__ __align__(16) float rbufA[64 * 68];
    __shared__ __align__(16) float rbufB[64 * 68];

    const int tid = threadIdx.x;
    const int lane = tid & 63, w = tid >> 6;
    const int q = lane >> 4, c = lane & 15;
    const int n0 = blockIdx.x * 64;

    if (tid < 64) {
        float s = 0.f;
        const float4v* xr = (const float4v*)(x + (size_t)(n0 + tid) * 16);
        #pragma unroll
        for (int k = 0; k < 4; k++) {
            float4v v = xr[k];
            float a0 = b2f(f2b(v.x)), a1 = b2f(f2b(v.y));
            float a2 = b2f(f2b(v.z)), a3 = b2f(f2b(v.w));
            s += a0 * a0 + a1 * a1 + a2 * a2 + a3 * a3;
        }
        x2c[tid] = 0.5f * LOG2E * s;
    }

    // x B-fragments for the 4 n-groups
    pafrag ax[4];
    #pragma unroll
    for (int nt = 0; nt < 4; nt++)
        ax[nt] = mkxfrag(x, (size_t)(n0 + nt * 16 + c), q);

    float4v acc[4][4];
    #pragma unroll
    for (int a = 0; a < 4; a++)
        #pragma unroll
        for (int nt = 0; nt < 4; nt++) acc[a][nt] = (float4v)(0.f);

    __syncthreads();   // x2c ready

    // ============ data: exp2(x.z*log2e - z2) @ W^T, wave-private 256 m ============
    const int mbase = w * 256;
    #pragma unroll 2
    for (int mb = 0; mb < 8; mb++) {
        const int m0 = mbase + mb * 32;
        pafrag bzA = ldrow(zb, m0, q, c);
        pafrag bzB = ldrow(zb, m0 + 16, q, c);
        float4v c0A = *(const float4v*)(nz2P + m0 + 4 * q);
        float4v c0B = *(const float4v*)(nz2P + m0 + 16 + 4 * q);
        short8 aw0 = *(const short8*)(Wtb + (size_t)(0 * 16 + c) * 1024 + m0 + q * 8);
        short8 aw1 = *(const short8*)(Wtb + (size_t)(1 * 16 + c) * 1024 + m0 + q * 8);
        short8 aw2 = *(const short8*)(Wtb + (size_t)(2 * 16 + c) * 1024 + m0 + q * 8);
        short8 aw3 = *(const short8*)(Wtb + (size_t)(3 * 16 + c) * 1024 + m0 + q * 8);
        #pragma unroll
        for (int nt = 0; nt < 4; nt++) {
            float4v dA = pmfma(bzA, ax[nt], c0A);
            float4v dB = pmfma(bzB, ax[nt], c0B);
            uint4v u;
            u[0] = pkbf(EXP2F(dA[0]), EXP2F(dA[1]));
            u[1] = pkbf(EXP2F(dA[2]), EXP2F(dA[3]));
            u[2] = pkbf(EXP2F(dB[0]), EXP2F(dB[1]));
            u[3] = pkbf(EXP2F(dB[2]), EXP2F(dB[3]));
            short8 pb = __builtin_bit_cast(short8, u);
            __builtin_amdgcn_s_setprio(1);
            acc[0][nt] = __builtin_amdgcn_mfma_f32_16x16x32_bf16(aw0, pb, acc[0][nt], 0, 0, 0);
            acc[1][nt] = __builtin_amdgcn_mfma_f32_16x16x32_bf16(aw1, pb, acc[1][nt], 0, 0, 0);
            acc[2][nt] = __builtin_amdgcn_mfma_f32_16x16x32_bf16(aw2, pb, acc[2][nt], 0, 0, 0);
            acc[3][nt] = __builtin_amdgcn_mfma_f32_16x16x32_bf16(aw3, pb, acc[3][nt], 0, 0, 0);
            __builtin_amdgcn_s_setprio(0);
        }
    }

    // scale data part by exp2(-x2[n])
    #pragma unroll
    for (int nt = 0; nt < 4; nt++) {
        float sxv = EXP2F(-x2c[nt * 16 + c]);
        #pragma unroll
        for (int a = 0; a < 4; a++) acc[a][nt] *= sxv;
    }

    // ============ prior: cos(2pi*(x.F/2pi + ph/2pi)) @ blockdiag(pws) ============
    const int lbase = w * 128;
    #pragma unroll 2
    for (int lb = 0; lb < 4; lb++) {
        const int l0 = lbase + lb * 32;
        pafrag bfA = ldrow(FbB, l0, q, c);
        pafrag bfB = ldrow(FbB, l0 + 16, q, c);
        float4v c0A = *(const float4v*)(phP + l0 + 4 * q);
        float4v c0B = *(const float4v*)(phP + l0 + 16 + 4 * q);
        short8 aw0 = *(const short8*)(BWd + (size_t)(0 * 16 + c) * 512 + l0 + q * 8);
        short8 aw1 = *(const short8*)(BWd + (size_t)(1 * 16 + c) * 512 + l0 + q * 8);
        short8 aw2 = *(const short8*)(BWd + (size_t)(2 * 16 + c) * 512 + l0 + q * 8);
        short8 aw3 = *(const short8*)(BWd + (size_t)(3 * 16 + c) * 512 + l0 + q * 8);
        #pragma unroll
        for (int nt = 0; nt < 4; nt++) {
            float4v dA = pmfma(bfA, ax[nt], c0A);
            float4v dB = pmfma(bfB, ax[nt], c0B);
            uint4v u;
            u[0] = pkbf(COSR(dA[0]), COSR(dA[1]));
            u[1] = pkbf(COSR(dA[2]), COSR(dA[3]));
            u[2] = pkbf(COSR(dB[0]), COSR(dB[1]));
            u[3] = pkbf(COSR(dB[2]), COSR(dB[3]));
            short8 pb = __builtin_bit_cast(short8, u);
            __builtin_amdgcn_s_setprio(1);
            acc[0][nt] = __builtin_amdgcn_mfma_f32_16x16x32_bf16(aw0, pb, acc[0][nt], 0, 0, 0);
            acc[1][nt] = __builtin_amdgcn_mfma_f32_16x16x32_bf16(aw1, pb, acc[1][nt], 0, 0, 0);
            acc[2][nt] = __builtin_amdgcn_mfma_f32_16x16x32_bf16(aw2, pb, acc[2][nt], 0, 0, 0);
            acc[3][nt] = __builtin_amdgcn_mfma_f32_16x16x32_bf16(aw3, pb, acc[3][nt], 0, 0, 0);
            __builtin_amdgcn_s_setprio(0);
        }
    }

    // ============ epilogue: reduce 4 wave-partials, store ============
    __syncthreads();
    if (w & 1) {                       // w1 -> A, w3 -> B
        float* rb = (w == 1) ? rbufA : rbufB;
        #pragma unroll
        for (int a = 0; a < 4; a++)
            #pragma unroll
            for (int nt = 0; nt < 4; nt++)
                #pragma unroll
                for (int r = 0; r < 4; r++)
                    rb[(a * 16 + 4 * q + r) * 68 + nt * 16 + c] = acc[a][nt][r];
    }
    __syncthreads();
    if (!(w & 1)) {                    // w0 += into A, w2 += into B
        float* rb = (w == 0) ? rbufA : rbufB;
        #pragma unroll
        for (int a = 0; a < 4; a++)
            #pragma unroll
            for (int nt = 0; nt < 4; nt++)
                #pragma unroll
                for (int r = 0; r < 4; r++) {
                    int idx = (a * 16 + 4 * q + r) * 68 + nt * 16 + c;
                    rb[idx] += acc[a][nt][r];
                }
    }
    __syncthreads();
    #pragma unroll
    for (int k = 0; k < 16; k++) {     // out = A + B, row-coalesced
        int idx = k * 256 + tid;
        int row = idx >> 6, nn = idx & 63;
        out[(size_t)row * N_PTS + n0 + nn] = rbufA[row * 68 + nn] + rbufB[row * 68 + nn];
    }
}

extern "C" void kernel_launch(void* const* d_in, const int* in_sizes, int n_in,
                              void* d_out, int out_size, void* d_ws, size_t ws_size,
                              hipStream_t stream) {
    const float* x  = (const float*)d_in[0];   // [65536][16]
    const float* z  = (const float*)d_in[1];   // [1024][16]
    const float* W  = (const float*)d_in[2];   // [8][8][1024] = [64][1024]
    const float* F  = (const float*)d_in[3];   // [8][16][64]
    const float* ph = (const float*)d_in[4];   // [8][64]
    const float* pw = (const float*)d_in[5];   // [8][8][64] = [64][64]
    float* out = (float*)d_out;                // [64][65536]

    char* ws = (char*)d_ws;
    short* zb   = (short*)(ws);            // 32768 B
    short* FbB  = (short*)(ws + 32768);    // 16384 B
    short* BWd  = (short*)(ws + 49152);    // 65536 B
    short* Wtb  = (short*)(ws + 114688);   // 131072 B
    float* nz2P = (float*)(ws + 245760);   // 4096 B
    float* phP  = (float*)(ws + 249856);   // 2048 B

    prep_kernel<<<486, 256, 0, stream>>>(z, W, F, pw, ph, zb, FbB, BWd, Wtb, nz2P, phP);
    fused_kernel<<<1024, 256, 0, stream>>>(x, zb, FbB, BWd, Wtb, nz2P, phP, out);
}

// Round 10
// 107.552 us; speedup vs baseline: 1.6658x; 1.0110x over previous
//
#include <hip/hip_runtime.h>
#include <hip/hip_bf16.h>

#define N_PTS 65536
#define LOG2E 1.4426950408889634f
#define INV2PI 0.15915494309189535f

typedef __attribute__((ext_vector_type(8))) short short8;
typedef __attribute__((ext_vector_type(4))) short short4v;
typedef __attribute__((ext_vector_type(4))) float float4v;
typedef __attribute__((ext_vector_type(4))) unsigned int uint4v;

#if __has_builtin(__builtin_amdgcn_exp2f)
#define EXP2F(x) __builtin_amdgcn_exp2f(x)
#else
#define EXP2F(x) exp2f(x)
#endif

// cos on REVOLUTIONS (inputs pre-scaled by 1/2pi in prep): v_fract + v_cos.
#if __has_builtin(__builtin_amdgcn_cosf) && __has_builtin(__builtin_amdgcn_fractf)
#define COSR(x) __builtin_amdgcn_cosf(__builtin_amdgcn_fractf(x))
#else
#define COSR(x) __cosf((x) * 6.283185307179586f)
#endif

__device__ __forceinline__ short f2b(float f) {
    __hip_bfloat16 h = __float2bfloat16(f);
    return *(short*)&h;
}
__device__ __forceinline__ float b2f(short s) {
    __hip_bfloat16 h = *(__hip_bfloat16*)&s;
    return __bfloat162float(h);
}

// Cheap packed f32x2 -> bf16x2: round-half-away (bits + 0x8000, truncate).
// Same 0.5-ulp bound as RNE; pure integer ops, 4 independent words of
// ~5 ops each (vs the ~14-op serial f2b+insert chain). Numerically
// validated in R7: identical absmax to the f2b chain. low16=a, high16=b.
__device__ __forceinline__ unsigned int pkbf(float a, float b) {
    unsigned int ua = __builtin_bit_cast(unsigned int, a) + 0x8000u;
    unsigned int ub = __builtin_bit_cast(unsigned int, b) + 0x8000u;
    return (ua >> 16) | (ub & 0xFFFF0000u);
}

// ---- producer MFMA: K=16 native if available, else masked 16x16x32.
#if __has_builtin(__builtin_amdgcn_mfma_f32_16x16x16bf16_1k)
#define HAVE_MFMA16 1
typedef short4v pafrag;
__device__ __forceinline__ float4v pmfma(pafrag a, pafrag b, float4v c) {
    return __builtin_amdgcn_mfma_f32_16x16x16bf16_1k(a, b, c, 0, 0, 0);
}
#else
#define HAVE_MFMA16 0
typedef short8 pafrag;
__device__ __forceinline__ float4v pmfma(pafrag a, pafrag b, float4v c) {
    return __builtin_amdgcn_mfma_f32_16x16x32_bf16(a, b, c, 0, 0, 0);
}
#endif

// A-fragment from a [rows][16] bf16 table: lane (q,c) -> row base+c, k-dims.
__device__ __forceinline__ pafrag ldrow(const short* base, int row16, int q, int c) {
#if HAVE_MFMA16
    return *(const pafrag*)(base + (size_t)(row16 + c) * 16 + 4 * q);
#else
    pafrag v = (pafrag)0;
    if (q < 2) v = *(const pafrag*)(base + (size_t)(row16 + c) * 16 + 8 * q);
    return v;
#endif
}
// B-fragment from x (f32 [n][16]): lane (q,c) -> col row, k-dims.
__device__ __forceinline__ pafrag mkxfrag(const float* x, size_t row, int q) {
#if HAVE_MFMA16
    float4v v = *(const float4v*)(x + row * 16 + 4 * q);
    pafrag a;
    a[0] = f2b(v.x); a[1] = f2b(v.y); a[2] = f2b(v.z); a[3] = f2b(v.w);
    return a;
#else
    pafrag a = (pafrag)0;
    if (q < 2) {
        const float4v* xp = (const float4v*)(x + row * 16 + 8 * q);
        float4v v0 = xp[0], v1 = xp[1];
        a[0] = f2b(v0.x); a[1] = f2b(v0.y); a[2] = f2b(v0.z); a[3] = f2b(v0.w);
        a[4] = f2b(v1.x); a[5] = f2b(v1.y); a[6] = f2b(v1.z); a[7] = f2b(v1.w);
    }
    return a;
#endif
}

// K-permutation: within each 32-row group, storage row p holds source row
// perm(p). Chunk A (p<16) -> m {0-3,8-11,16-19,24-27}; chunk B -> +4.
// Producer D-reg r at lane q (chunk A row 4q+r) => m = 8q+r; chunk B => 8q+4+r.
// So [dA[0..3], dB[0..3]] at lane q == consumer B-fragment k = 8q..8q+7. No LDS.
__device__ __forceinline__ int permrow(int p) {
    return ((p & 12) << 1) + (p & 3) + ((p >> 4) << 2);
}

// ---------------- prep (unchanged) ----------------
// ws layout (bytes):
//   zb   [1024][16] bf16  @ 0        row-PERMUTED bf16(log2e * z)
//   FbB  [512][16] bf16   @ 32768    row-PERMUTED bf16(F^T / 2pi)  (rows = o*64+l)
//   BWd  [64][512] bf16   @ 49152    block-diag sqrt(2/64)*pw (natural cols)
//   Wtb  [64][1024] bf16  @ 114688   bf16(W) (natural cols)
//   nz2P [1024] f32       @ 245760   PERMUTED  -0.5*log2e*||bf16(z_m)||^2
//   phP  [512] f32        @ 249856   PERMUTED  phases / 2pi
__global__ __launch_bounds__(256) void prep_kernel(
    const float* __restrict__ z, const float* __restrict__ W,
    const float* __restrict__ F, const float* __restrict__ pw,
    const float* __restrict__ ph,
    short* __restrict__ zb, short* __restrict__ FbB,
    short* __restrict__ BWd, short* __restrict__ Wtb,
    float* __restrict__ nz2P, float* __restrict__ phP)
{
    int t = blockIdx.x * 256 + threadIdx.x;
    if (t < 16384) {
        int row = t >> 4, i = t & 15;
        int src = (row & ~31) + permrow(row & 31);
        zb[t] = f2b(LOG2E * z[src * 16 + i]);
    } else if (t < 17408) {
        int m = t - 16384;
        int src = (m & ~31) + permrow(m & 31);
        const float4v* zp = (const float4v*)(z + (size_t)src * 16);
        float s = 0.f;
        #pragma unroll
        for (int k = 0; k < 4; k++) {
            float4v v = zp[k];
            float a0 = b2f(f2b(v.x)), a1 = b2f(f2b(v.y));
            float a2 = b2f(f2b(v.z)), a3 = b2f(f2b(v.w));
            s += a0 * a0 + a1 * a1 + a2 * a2 + a3 * a3;
        }
        nz2P[m] = -(0.5f * LOG2E * s);
    } else if (t < 25600) {
        int p = t - 17408;
        int row = p >> 4, i = p & 15;
        int srow = (row & ~31) + permrow(row & 31);
        int o = srow >> 6, l = srow & 63;
        FbB[p] = f2b(INV2PI * F[o * 1024 + i * 64 + l]);
    } else if (t < 58368) {
        int p = t - 25600;
        int so = p >> 9, ol = p & 511, o = ol >> 6;
        float v = ((so & 7) == o) ? 0.17677669529663687f * pw[so * 64 + (ol & 63)] : 0.f;
        BWd[p] = f2b(v);
    } else if (t < 123904) {
        int p = t - 58368;
        Wtb[p] = f2b(W[p]);
    } else {
        int j = t - 123904;                    // 512 phases
        int sj = (j & ~31) + permrow(j & 31);
        phP[j] = INV2PI * ph[sj];
    }
}

// ---------------- fused prior + data: register-direct, zero main-loop LDS ----
// EXACT R6 structure (best: 45us fused): 4 waves, K-quarter each, 64 so x
// 64 n, nt-outer consumer, bounds(256,4), unroll 2, NO setprio (R8/R9
// evidence: the setprio fence serializes nt chains). Single change vs R6:
// pkbf pack replaces the f2b chain on the producer->consumer critical path.
__global__ __launch_bounds__(256, 4) void fused_kernel(
    const float* __restrict__ x,
    const short* __restrict__ zb, const short* __restrict__ FbB,
    const short* __restrict__ BWd, const short* __restrict__ Wtb,
    const float* __restrict__ nz2P, const float* __restrict__ phP,
    float* __restrict__ out)
{
    __shared__ float x2c[64];
    __shared__ __align__(16) float rbufA[64 * 68];
    __shared__ __align__(16) float rbufB[64 * 68];

    const int tid = threadIdx.x;
    const int lane = tid & 63, w = tid >> 6;
    const int q = lane >> 4, c = lane & 15;
    const int n0 = blockIdx.x * 64;

    if (tid < 64) {
        float s = 0.f;
        const float4v* xr = (const float4v*)(x + (size_t)(n0 + tid) * 16);
        #pragma unroll
        for (int k = 0; k < 4; k++) {
            float4v v = xr[k];
            float a0 = b2f(f2b(v.x)), a1 = b2f(f2b(v.y));
            float a2 = b2f(f2b(v.z)), a3 = b2f(f2b(v.w));
            s += a0 * a0 + a1 * a1 + a2 * a2 + a3 * a3;
        }
        x2c[tid] = 0.5f * LOG2E * s;
    }

    // x B-fragments for the 4 n-groups
    pafrag ax[4];
    #pragma unroll
    for (int nt = 0; nt < 4; nt++)
        ax[nt] = mkxfrag(x, (size_t)(n0 + nt * 16 + c), q);

    float4v acc[4][4];
    #pragma unroll
    for (int a = 0; a < 4; a++)
        #pragma unroll
        for (int nt = 0; nt < 4; nt++) acc[a][nt] = (float4v)(0.f);

    __syncthreads();   // x2c ready

    // ============ data: exp2(x.z*log2e - z2) @ W^T, wave-private 256 m ============
    const int mbase = w * 256;
    #pragma unroll 2
    for (int mb = 0; mb < 8; mb++) {
        const int m0 = mbase + mb * 32;
        pafrag bzA = ldrow(zb, m0, q, c);
        pafrag bzB = ldrow(zb, m0 + 16, q, c);
        float4v c0A = *(const float4v*)(nz2P + m0 + 4 * q);
        float4v c0B = *(const float4v*)(nz2P + m0 + 16 + 4 * q);
        short8 aw0 = *(const short8*)(Wtb + (size_t)(0 * 16 + c) * 1024 + m0 + q * 8);
        short8 aw1 = *(const short8*)(Wtb + (size_t)(1 * 16 + c) * 1024 + m0 + q * 8);
        short8 aw2 = *(const short8*)(Wtb + (size_t)(2 * 16 + c) * 1024 + m0 + q * 8);
        short8 aw3 = *(const short8*)(Wtb + (size_t)(3 * 16 + c) * 1024 + m0 + q * 8);
        #pragma unroll
        for (int nt = 0; nt < 4; nt++) {
            float4v dA = pmfma(bzA, ax[nt], c0A);
            float4v dB = pmfma(bzB, ax[nt], c0B);
            uint4v u;
            u[0] = pkbf(EXP2F(dA[0]), EXP2F(dA[1]));
            u[1] = pkbf(EXP2F(dA[2]), EXP2F(dA[3]));
            u[2] = pkbf(EXP2F(dB[0]), EXP2F(dB[1]));
            u[3] = pkbf(EXP2F(dB[2]), EXP2F(dB[3]));
            short8 pb = __builtin_bit_cast(short8, u);
            acc[0][nt] = __builtin_amdgcn_mfma_f32_16x16x32_bf16(aw0, pb, acc[0][nt], 0, 0, 0);
            acc[1][nt] = __builtin_amdgcn_mfma_f32_16x16x32_bf16(aw1, pb, acc[1][nt], 0, 0, 0);
            acc[2][nt] = __builtin_amdgcn_mfma_f32_16x16x32_bf16(aw2, pb, acc[2][nt], 0, 0, 0);
            acc[3][nt] = __builtin_amdgcn_mfma_f32_16x16x32_bf16(aw3, pb, acc[3][nt], 0, 0, 0);
        }
    }

    // scale data part by exp2(-x2[n])
    #pragma unroll
    for (int nt = 0; nt < 4; nt++) {
        float sxv = EXP2F(-x2c[nt * 16 + c]);
        #pragma unroll
        for (int a = 0; a < 4; a++) acc[a][nt] *= sxv;
    }

    // ============ prior: cos(2pi*(x.F/2pi + ph/2pi)) @ blockdiag(pws) ============
    const int lbase = w * 128;
    #pragma unroll 2
    for (int lb = 0; lb < 4; lb++) {
        const int l0 = lbase + lb * 32;
        pafrag bfA = ldrow(FbB, l0, q, c);
        pafrag bfB = ldrow(FbB, l0 + 16, q, c);
        float4v c0A = *(const float4v*)(phP + l0 + 4 * q);
        float4v c0B = *(const float4v*)(phP + l0 + 16 + 4 * q);
        short8 aw0 = *(const short8*)(BWd + (size_t)(0 * 16 + c) * 512 + l0 + q * 8);
        short8 aw1 = *(const short8*)(BWd + (size_t)(1 * 16 + c) * 512 + l0 + q * 8);
        short8 aw2 = *(const short8*)(BWd + (size_t)(2 * 16 + c) * 512 + l0 + q * 8);
        short8 aw3 = *(const short8*)(BWd + (size_t)(3 * 16 + c) * 512 + l0 + q * 8);
        #pragma unroll
        for (int nt = 0; nt < 4; nt++) {
            float4v dA = pmfma(bfA, ax[nt], c0A);
            float4v dB = pmfma(bfB, ax[nt], c0B);
            uint4v u;
            u[0] = pkbf(COSR(dA[0]), COSR(dA[1]));
            u[1] = pkbf(COSR(dA[2]), COSR(dA[3]));
            u[2] = pkbf(COSR(dB[0]), COSR(dB[1]));
            u[3] = pkbf(COSR(dB[2]), COSR(dB[3]));
            short8 pb = __builtin_bit_cast(short8, u);
            acc[0][nt] = __builtin_amdgcn_mfma_f32_16x16x32_bf16(aw0, pb, acc[0][nt], 0, 0, 0);
            acc[1][nt] = __builtin_amdgcn_mfma_f32_16x16x32_bf16(aw1, pb, acc[1][nt], 0, 0, 0);
            acc[2][nt] = __builtin_amdgcn_mfma_f32_16x16x32_bf16(aw2, pb, acc[2][nt], 0, 0, 0);
            acc[3][nt] = __builtin_amdgcn_mfma_f32_16x16x32_bf16(aw3, pb, acc[3][nt], 0, 0, 0);
        }
    }

    // ============ epilogue: reduce 4 wave-partials, store ============
    __syncthreads();
    if (w & 1) {                       // w1 -> A, w3 -> B
        float* rb = (w == 1) ? rbufA : rbufB;
        #pragma unroll
        for (int a = 0; a < 4; a++)
            #pragma unroll
            for (int nt = 0; nt < 4; nt++)
                #pragma unroll
                for (int r = 0; r < 4; r++)
                    rb[(a * 16 + 4 * q + r) * 68 + nt * 16 + c] = acc[a][nt][r];
    }
    __syncthreads();
    if (!(w & 1)) {                    // w0 += into A, w2 += into B
        float* rb = (w == 0) ? rbufA : rbufB;
        #pragma unroll
        for (int a = 0; a < 4; a++)
            #pragma unroll
            for (int nt = 0; nt < 4; nt++)
                #pragma unroll
                for (int r = 0; r < 4; r++) {
                    int idx = (a * 16 + 4 * q + r) * 68 + nt * 16 + c;
                    rb[idx] += acc[a][nt][r];
                }
    }
    __syncthreads();
    #pragma unroll
    for (int k = 0; k < 16; k++) {     // out = A + B, row-coalesced
        int idx = k * 256 + tid;
        int row = idx >> 6, nn = idx & 63;
        out[(size_t)row * N_PTS + n0 + nn] = rbufA[row * 68 + nn] + rbufB[row * 68 + nn];
    }
}

extern "C" void kernel_launch(void* const* d_in, const int* in_sizes, int n_in,
                              void* d_out, int out_size, void* d_ws, size_t ws_size,
                              hipStream_t stream) {
    const float* x  = (const float*)d_in[0];   // [65536][16]
    const float* z  = (const float*)d_in[1];   // [1024][16]
    const float* W  = (const float*)d_in[2];   // [8][8][1024] = [64][1024]
    const float* F  = (const float*)d_in[3];   // [8][16][64]
    const float* ph = (const float*)d_in[4];   // [8][64]
    const float* pw = (const float*)d_in[5];   // [8][8][64] = [64][64]
    float* out = (float*)d_out;                // [64][65536]

    char* ws = (char*)d_ws;
    short* zb   = (short*)(ws);            // 32768 B
    short* FbB  = (short*)(ws + 32768);    // 16384 B
    short* BWd  = (short*)(ws + 49152);    // 65536 B
    short* Wtb  = (short*)(ws + 114688);   // 131072 B
    float* nz2P = (float*)(ws + 245760);   // 4096 B
    float* phP  = (float*)(ws + 249856);   // 2048 B

    prep_kernel<<<486, 256, 0, stream>>>(z, W, F, pw, ph, zb, FbB, BWd, Wtb, nz2P, phP);
    fused_kernel<<<1024, 256, 0, stream>>>(x, zb, FbB, BWd, Wtb, nz2P, phP, out);
}